// Round 1
// baseline (282.281 us; speedup 1.0000x reference)
//
#include <hip/hip_runtime.h>

typedef unsigned short u16;
typedef unsigned int   u32;
typedef __bf16 bf16x8 __attribute__((ext_vector_type(8)));
typedef float  f32x4  __attribute__((ext_vector_type(4)));

#define T_TOT  65536
#define NSEG   64
#define NH     16
#define DD     128
#define LL     64
#define BT     64
#define LDA    136   // row stride in u16 elems (128 data + 8 pad) = 272B -> conflict-free b128 reads
#define SCALE  11.313708498984761f   // sqrt(128)

__device__ __forceinline__ u16 f2bf_rne(float x){
    u32 u = __float_as_uint(x);
    u32 r = u + 0x7fffu + ((u >> 16) & 1u);
    return (u16)(r >> 16);
}
__device__ __forceinline__ float bf2f(u16 h){
    return __uint_as_float(((u32)h) << 16);
}
// tanh(x) = 1 - 2/(1+e^{2x}); saturates correctly via exp2 overflow/underflow
__device__ __forceinline__ float fast_tanh(float x){
    float e = __builtin_amdgcn_exp2f(x * 2.8853900817779268f);  // 2*log2(e)
    return 1.0f - 2.0f * __builtin_amdgcn_rcpf(1.0f + e);
}

// ---------------- prep: split V into bf16 hi/lo ----------------
__global__ void prep_split(const float* __restrict__ V,
                           u16* __restrict__ Vh, u16* __restrict__ Vl){
    int idx = blockIdx.x * 256 + threadIdx.x;   // H*L*D = 131072 total
    float x = V[idx];
    u16 hi = f2bf_rne(x);
    Vh[idx] = hi;
    Vl[idx] = f2bf_rne(x - bf2f(hi));
}

// ---------------- main: lamb via MFMA (bf16x3), e=exp, segment-partial sums ----------------
__global__ __launch_bounds__(256, 2) void medvid_main(
    const float* __restrict__ videos, const int* __restrict__ segids,
    const u16* __restrict__ Vh, const u16* __restrict__ Vl,
    const float* __restrict__ w,
    float* __restrict__ hsum, float* __restrict__ denom)
{
    __shared__ u16 sAh[BT * LDA];
    __shared__ u16 sAl[BT * LDA];
    __shared__ u16 sBh[LL * LDA];
    __shared__ u16 sBl[LL * LDA];
    __shared__ float se[BT];
    __shared__ int   sseg[BT];
    __shared__ float sden[NSEG];

    const int tid = threadIdx.x;
    const int h   = blockIdx.y;
    const int bt0 = blockIdx.x * BT;

    // ---- stage A: videos[bt0..+64, h*128..+128] fp32 -> bf16 hi/lo in LDS ----
    #pragma unroll
    for (int i = 0; i < 8; ++i){
        int idx = i * 256 + tid;            // 0..2047
        int t = idx >> 5, q = idx & 31;     // 32 float4 per frame-row
        const float4 v = *(const float4*)(videos + (size_t)(bt0 + t) * 2048 + h * DD + q * 4);
        u16 h0 = f2bf_rne(v.x), h1 = f2bf_rne(v.y), h2 = f2bf_rne(v.z), h3 = f2bf_rne(v.w);
        u16 l0 = f2bf_rne(v.x - bf2f(h0));
        u16 l1 = f2bf_rne(v.y - bf2f(h1));
        u16 l2 = f2bf_rne(v.z - bf2f(h2));
        u16 l3 = f2bf_rne(v.w - bf2f(h3));
        *(ushort4*)(sAh + t * LDA + q * 4) = make_ushort4(h0, h1, h2, h3);
        *(ushort4*)(sAl + t * LDA + q * 4) = make_ushort4(l0, l1, l2, l3);
    }
    // ---- stage B: V[h] hi/lo (64 x 128 bf16 each) ----
    #pragma unroll
    for (int i = 0; i < 4; ++i){
        int idx = i * 256 + tid;            // 0..1023
        int l = idx >> 4, c = idx & 15;     // 16B chunks per row
        *(uint4*)(sBh + l * LDA + c * 8) = *(const uint4*)(Vh + ((h * LL + l) * DD) + c * 8);
        *(uint4*)(sBl + l * LDA + c * 8) = *(const uint4*)(Vl + ((h * LL + l) * DD) + c * 8);
    }
    if (tid < BT)   sseg[tid] = segids[bt0 + tid];
    if (tid < NSEG) sden[tid] = 0.0f;
    __syncthreads();

    // ---- MFMA: pre-tanh alpha tile [64 frames x 64 L], per-wave 16-frame M-tile ----
    const int lane = tid & 63;
    const int wv   = tid >> 6;      // wave id = M-tile
    const int col  = lane & 15;     // A-row / B-col / C-col
    const int kb   = lane >> 4;     // k-block

    f32x4 acc[4] = {};
    const u16* aph = sAh + (wv * 16 + col) * LDA + kb * 8;
    const u16* apl = sAl + (wv * 16 + col) * LDA + kb * 8;
    #pragma unroll
    for (int ks = 0; ks < 4; ++ks){
        const int ko = ks * 32;
        bf16x8 aH = *(const bf16x8*)(aph + ko);
        bf16x8 aL = *(const bf16x8*)(apl + ko);
        #pragma unroll
        for (int nt = 0; nt < 4; ++nt){
            const u16* bph = sBh + (nt * 16 + col) * LDA + kb * 8 + ko;
            const u16* bpl = sBl + (nt * 16 + col) * LDA + kb * 8 + ko;
            bf16x8 bH = *(const bf16x8*)bph;
            bf16x8 bL = *(const bf16x8*)bpl;
            acc[nt] = __builtin_amdgcn_mfma_f32_16x16x32_bf16(aH, bH, acc[nt], 0, 0, 0);
            acc[nt] = __builtin_amdgcn_mfma_f32_16x16x32_bf16(aL, bH, acc[nt], 0, 0, 0);
            acc[nt] = __builtin_amdgcn_mfma_f32_16x16x32_bf16(aH, bL, acc[nt], 0, 0, 0);
        }
    }

    // ---- tanh -> *w -> row-sum over L (butterfly within 16-lane col groups) -> e = exp(lamb) ----
    float wl[4];
    #pragma unroll
    for (int nt = 0; nt < 4; ++nt) wl[nt] = w[h * LL + nt * 16 + col];
    float srow[4] = {0.f, 0.f, 0.f, 0.f};
    #pragma unroll
    for (int nt = 0; nt < 4; ++nt){
        #pragma unroll
        for (int r = 0; r < 4; ++r)
            srow[r] += fast_tanh(acc[nt][r]) * wl[nt];
    }
    #pragma unroll
    for (int r = 0; r < 4; ++r){
        #pragma unroll
        for (int m = 1; m < 16; m <<= 1)
            srow[r] += __shfl_xor(srow[r], m, 64);
    }
    if (col == 0){
        #pragma unroll
        for (int r = 0; r < 4; ++r){
            int t = wv * 16 + kb * 4 + r;   // C/D: row = (lane>>4)*4 + r
            se[t] = __builtin_amdgcn_exp2f(srow[r] * 1.4426950408889634f);
        }
    }
    __syncthreads();

    // ---- segment partial sums: hsum[s][h][d] += e_t * hq[t][d];  (sorted segs -> rare flushes) ----
    {
        const int dp  = tid & 63;      // d-pair: d = 2*dp, 2*dp+1
        const int grp = tid >> 6;      // 4 groups x 16 frames
        float ax = 0.f, ay = 0.f;
        int cur = sseg[grp * 16];
        #pragma unroll
        for (int j = 0; j < 16; ++j){
            int t = grp * 16 + j;
            int s = sseg[t];           // wave-uniform
            if (s != cur){
                float* dst = hsum + ((size_t)cur * NH + h) * DD + dp * 2;
                atomicAdd(dst, ax); atomicAdd(dst + 1, ay);
                ax = 0.f; ay = 0.f; cur = s;
            }
            float ev = se[t];
            u32 uh = *(const u32*)(sAh + t * LDA + dp * 2);
            u32 ul = *(const u32*)(sAl + t * LDA + dp * 2);
            ax += ev * (bf2f((u16)(uh & 0xffffu)) + bf2f((u16)(ul & 0xffffu)));
            ay += ev * (bf2f((u16)(uh >> 16))     + bf2f((u16)(ul >> 16)));
        }
        float* dst = hsum + ((size_t)cur * NH + h) * DD + dp * 2;
        atomicAdd(dst, ax); atomicAdd(dst + 1, ay);
    }
    // ---- denominators: per-block LDS reduce, then one global atomic per present segment ----
    if (tid < BT) atomicAdd(&sden[sseg[tid]], se[tid]);
    __syncthreads();
    if (tid < NSEG){
        float v = sden[tid];
        if (v != 0.0f) atomicAdd(&denom[tid * NH + h], v);
    }
}

// ---------------- finalize: h_study = hsum/(denom*SCALE); out[s] = h_study . W_out + b ----------------
__global__ void finalize(const float* __restrict__ hsum, const float* __restrict__ denom,
                         const float* __restrict__ W_out, const float* __restrict__ b_out,
                         float* __restrict__ out)
{
    const int s = blockIdx.x;
    const int tid = threadIdx.x;
    float part = 0.f;
    for (int f = tid; f < 2048; f += 256){
        int hh = f >> 7, d = f & 127;
        float den = denom[s * NH + hh];
        if (den > 0.f)
            part += hsum[((size_t)s * NH + hh) * DD + d] / (den * SCALE) * W_out[f];
    }
    #pragma unroll
    for (int m = 1; m < 64; m <<= 1) part += __shfl_xor(part, m, 64);
    __shared__ float red[4];
    if ((tid & 63) == 0) red[tid >> 6] = part;
    __syncthreads();
    if (tid == 0) out[s] = red[0] + red[1] + red[2] + red[3] + b_out[0];
}

extern "C" void kernel_launch(void* const* d_in, const int* in_sizes, int n_in,
                              void* d_out, int out_size, void* d_ws, size_t ws_size,
                              hipStream_t stream)
{
    const float* videos = (const float*)d_in[0];
    const int*   segids = (const int*)  d_in[1];
    const float* V      = (const float*)d_in[2];
    const float* w      = (const float*)d_in[3];
    const float* W_out  = (const float*)d_in[4];
    const float* b_out  = (const float*)d_in[5];
    float* out = (float*)d_out;

    // ws layout: hsum[S*H*D] f32 | denom[S*H] f32 | Vh[H*L*D] u16 | Vl[H*L*D] u16  (~1.03 MB)
    float* hsum  = (float*)d_ws;
    float* denom = hsum + (NSEG * NH * DD);
    u16*   Vh    = (u16*)(denom + NSEG * NH);
    u16*   Vl    = Vh + (NH * LL * DD);

    hipMemsetAsync(d_ws, 0, (size_t)(NSEG * NH * DD + NSEG * NH) * sizeof(float), stream);
    prep_split<<<dim3((NH * LL * DD) / 256), dim3(256), 0, stream>>>(V, Vh, Vl);
    medvid_main<<<dim3(T_TOT / BT, NH), dim3(256), 0, stream>>>(videos, segids, Vh, Vl, w, hsum, denom);
    finalize<<<dim3(NSEG), dim3(256), 0, stream>>>(hsum, denom, W_out, b_out, out);
}

// Round 2
// 221.804 us; speedup vs baseline: 1.2727x; 1.2727x over previous
//
#include <hip/hip_runtime.h>

typedef unsigned short u16;
typedef unsigned int   u32;
typedef __bf16 bf16x8 __attribute__((ext_vector_type(8)));
typedef u16    u16x8  __attribute__((ext_vector_type(8)));
typedef float  f32x4  __attribute__((ext_vector_type(4)));

#define T_TOT  65536
#define NSEG   64
#define NH     16
#define DD     128
#define LL     64
#define BT     64
#define LDA    136   // row stride in u16 (128 data + 8 pad) = 272B
#define SCALE  11.313708498984761f   // sqrt(128)

__device__ __forceinline__ u16 f2bf_rne(float x){
    u32 u = __float_as_uint(x);
    u32 r = u + 0x7fffu + ((u >> 16) & 1u);
    return (u16)(r >> 16);
}
__device__ __forceinline__ float bf2f(u16 h){
    return __uint_as_float(((u32)h) << 16);
}
__device__ __forceinline__ float fast_tanh(float x){
    float e = __builtin_amdgcn_exp2f(x * 2.8853900817779268f);  // 2*log2(e)
    return 1.0f - 2.0f * __builtin_amdgcn_rcpf(1.0f + e);
}

// split 8 fp32 -> bf16 hi + bf16 lo (error-compensated), fully in registers
__device__ __forceinline__ void cvt8(const float4 a, const float4 b,
                                     bf16x8& hi, bf16x8& lo){
    float xs[8] = {a.x, a.y, a.z, a.w, b.x, b.y, b.z, b.w};
    union { u16x8 u; bf16x8 b; } H, L;
    #pragma unroll
    for (int j = 0; j < 8; ++j){
        u32 u = __float_as_uint(xs[j]);
        u32 r = u + 0x7fffu + ((u >> 16) & 1u);
        H.u[j] = (u16)(r >> 16);
        float d = xs[j] - __uint_as_float(r & 0xffff0000u);
        u32 v = __float_as_uint(d);
        u32 s = v + 0x7fffu + ((v >> 16) & 1u);
        L.u[j] = (u16)(s >> 16);
    }
    hi = H.b; lo = L.b;
}

// ---------------- prep: split V into bf16 hi/lo + zero accumulators ----------------
__global__ void prep_split(const float* __restrict__ V,
                           u16* __restrict__ Vh, u16* __restrict__ Vl,
                           float* __restrict__ hsum, float* __restrict__ denom){
    int idx = blockIdx.x * 256 + threadIdx.x;   // 131072 threads total
    float x = V[idx];
    u16 hi = f2bf_rne(x);
    Vh[idx] = hi;
    Vl[idx] = f2bf_rne(x - bf2f(hi));
    hsum[idx] = 0.0f;                            // hsum is exactly 64*16*128 = 131072
    if (idx < NSEG * NH) denom[idx] = 0.0f;
}

// ---------------- main ----------------
__global__ __launch_bounds__(256, 3) void medvid_main(
    const float* __restrict__ videos, const int* __restrict__ segids,
    const u16* __restrict__ Vh, const u16* __restrict__ Vl,
    const float* __restrict__ w,
    float* __restrict__ hsum, float* __restrict__ denom)
{
    __shared__ u16 sAh[BT * LDA];   // A-hi tile, filled in MFMA frag layout (17.4 KB)
    __shared__ u16 sBh[LL * LDA];
    __shared__ u16 sBl[LL * LDA];
    __shared__ float se[BT];
    __shared__ int   sseg[BT];
    __shared__ float sden[NSEG];

    const int tid  = threadIdx.x;
    const int h    = blockIdx.y;
    const int bt0  = blockIdx.x * BT;
    const int lane = tid & 63;
    const int wv   = tid >> 6;      // wave id = 16-frame M-tile
    const int col  = lane & 15;     // A-row / B-col / C-col
    const int kb   = lane >> 4;     // k-block

    // ---- A fragment loads straight from global (fp32), issued up front ----
    const float* arow = videos + (size_t)(bt0 + wv * 16 + col) * 2048 + h * DD + kb * 8;
    float4 av[8];
    #pragma unroll
    for (int ks = 0; ks < 4; ++ks){
        av[2 * ks]     = *(const float4*)(arow + ks * 32);
        av[2 * ks + 1] = *(const float4*)(arow + ks * 32 + 4);
    }

    // ---- stage B: V[h] hi/lo (64 x 128 bf16 each) ----
    #pragma unroll
    for (int i = 0; i < 4; ++i){
        int idx = i * 256 + tid;            // 0..1023
        int l = idx >> 4, c = idx & 15;
        *(uint4*)(sBh + l * LDA + c * 8) = *(const uint4*)(Vh + ((h * LL + l) * DD) + c * 8);
        *(uint4*)(sBl + l * LDA + c * 8) = *(const uint4*)(Vl + ((h * LL + l) * DD) + c * 8);
    }
    if (tid < BT)   sseg[tid] = segids[bt0 + tid];
    if (tid < NSEG) sden[tid] = 0.0f;
    __syncthreads();

    // ---- MFMA: alpha pre-tanh [64 x 64], bf16x3 compensated ----
    f32x4 acc[4] = {};
    #pragma unroll
    for (int ks = 0; ks < 4; ++ks){
        bf16x8 aH, aL;
        cvt8(av[2 * ks], av[2 * ks + 1], aH, aL);
        const int ko = kb * 8 + ks * 32;
        // park hi in LDS for the phase-4 e*hq rebuild (same frag address it was computed for)
        *(bf16x8*)(sAh + (wv * 16 + col) * LDA + ko) = aH;
        #pragma unroll
        for (int nt = 0; nt < 4; ++nt){
            bf16x8 bH = *(const bf16x8*)(sBh + (nt * 16 + col) * LDA + ko);
            bf16x8 bL = *(const bf16x8*)(sBl + (nt * 16 + col) * LDA + ko);
            acc[nt] = __builtin_amdgcn_mfma_f32_16x16x32_bf16(aH, bH, acc[nt], 0, 0, 0);
            acc[nt] = __builtin_amdgcn_mfma_f32_16x16x32_bf16(aL, bH, acc[nt], 0, 0, 0);
            acc[nt] = __builtin_amdgcn_mfma_f32_16x16x32_bf16(aH, bL, acc[nt], 0, 0, 0);
        }
    }

    // ---- tanh -> *w -> row-sum over L -> e = exp(lamb) ----
    float wl[4];
    #pragma unroll
    for (int nt = 0; nt < 4; ++nt) wl[nt] = w[h * LL + nt * 16 + col];
    float srow[4] = {0.f, 0.f, 0.f, 0.f};
    #pragma unroll
    for (int nt = 0; nt < 4; ++nt){
        #pragma unroll
        for (int r = 0; r < 4; ++r)
            srow[r] += fast_tanh(acc[nt][r]) * wl[nt];
    }
    #pragma unroll
    for (int r = 0; r < 4; ++r){
        #pragma unroll
        for (int m = 1; m < 16; m <<= 1)
            srow[r] += __shfl_xor(srow[r], m, 64);
    }
    if (col == 0){
        #pragma unroll
        for (int r = 0; r < 4; ++r){
            int t = wv * 16 + kb * 4 + r;   // C/D: row = (lane>>4)*4 + r
            se[t] = __builtin_amdgcn_exp2f(srow[r] * 1.4426950408889634f);
        }
    }
    __syncthreads();

    // ---- segment partial sums from A-hi: hsum[s][h][d] += e_t * hq[t][d] ----
    {
        const int dp  = tid & 63;      // d-pair: d = 2*dp, 2*dp+1
        const int grp = tid >> 6;      // 4 groups x 16 frames (own wave's rows)
        float ax = 0.f, ay = 0.f;
        int cur = sseg[grp * 16];
        #pragma unroll
        for (int j = 0; j < 16; ++j){
            int t = grp * 16 + j;
            int s = sseg[t];           // wave-uniform
            if (s != cur){
                float* dst = hsum + ((size_t)cur * NH + h) * DD + dp * 2;
                atomicAdd(dst, ax); atomicAdd(dst + 1, ay);
                ax = 0.f; ay = 0.f; cur = s;
            }
            float ev = se[t];
            u32 uh = *(const u32*)(sAh + t * LDA + dp * 2);
            ax += ev * __uint_as_float(uh << 16);
            ay += ev * __uint_as_float(uh & 0xffff0000u);
        }
        float* dst = hsum + ((size_t)cur * NH + h) * DD + dp * 2;
        atomicAdd(dst, ax); atomicAdd(dst + 1, ay);
    }
    // ---- denominators ----
    if (tid < BT) atomicAdd(&sden[sseg[tid]], se[tid]);
    __syncthreads();
    if (tid < NSEG){
        float v = sden[tid];
        if (v != 0.0f) atomicAdd(&denom[tid * NH + h], v);
    }
}

// ---------------- finalize ----------------
__global__ void finalize(const float* __restrict__ hsum, const float* __restrict__ denom,
                         const float* __restrict__ W_out, const float* __restrict__ b_out,
                         float* __restrict__ out)
{
    const int s = blockIdx.x;
    const int tid = threadIdx.x;
    float part = 0.f;
    for (int f = tid; f < 2048; f += 256){
        int hh = f >> 7, d = f & 127;
        float den = denom[s * NH + hh];
        if (den > 0.f)
            part += hsum[((size_t)s * NH + hh) * DD + d] / (den * SCALE) * W_out[f];
    }
    #pragma unroll
    for (int m = 1; m < 64; m <<= 1) part += __shfl_xor(part, m, 64);
    __shared__ float red[4];
    if ((tid & 63) == 0) red[tid >> 6] = part;
    __syncthreads();
    if (tid == 0) out[s] = red[0] + red[1] + red[2] + red[3] + b_out[0];
}

extern "C" void kernel_launch(void* const* d_in, const int* in_sizes, int n_in,
                              void* d_out, int out_size, void* d_ws, size_t ws_size,
                              hipStream_t stream)
{
    const float* videos = (const float*)d_in[0];
    const int*   segids = (const int*)  d_in[1];
    const float* V      = (const float*)d_in[2];
    const float* w      = (const float*)d_in[3];
    const float* W_out  = (const float*)d_in[4];
    const float* b_out  = (const float*)d_in[5];
    float* out = (float*)d_out;

    // ws layout: hsum[S*H*D] f32 | denom[S*H] f32 | Vh[H*L*D] u16 | Vl[H*L*D] u16
    float* hsum  = (float*)d_ws;
    float* denom = hsum + (NSEG * NH * DD);
    u16*   Vh    = (u16*)(denom + NSEG * NH);
    u16*   Vl    = Vh + (NH * LL * DD);

    prep_split<<<dim3((NH * LL * DD) / 256), dim3(256), 0, stream>>>(V, Vh, Vl, hsum, denom);
    medvid_main<<<dim3(T_TOT / BT, NH), dim3(256), 0, stream>>>(videos, segids, Vh, Vl, w, hsum, denom);
    finalize<<<dim3(NSEG), dim3(256), 0, stream>>>(hsum, denom, W_out, b_out, out);
}

// Round 3
// 163.271 us; speedup vs baseline: 1.7289x; 1.3585x over previous
//
#include <hip/hip_runtime.h>

typedef unsigned short u16;
typedef unsigned int   u32;
typedef __bf16 bf16x8 __attribute__((ext_vector_type(8)));
typedef u16    u16x8  __attribute__((ext_vector_type(8)));
typedef float  f32x4  __attribute__((ext_vector_type(4)));

#define T_TOT  65536
#define NSEG   64
#define NH     16
#define DD     128
#define LL     64
#define BT     64
#define CHUNK  512           // frames per block
#define NTILE  8             // CHUNK / BT
#define NCHUNK 128           // T_TOT / CHUNK
#define LDA    136           // u16 row stride (272 B) -> conflict-free
#define SCALE  11.313708498984761f   // sqrt(128)

__device__ __forceinline__ u16 f2bf_rne(float x){
    u32 u = __float_as_uint(x);
    u32 r = u + 0x7fffu + ((u >> 16) & 1u);
    return (u16)(r >> 16);
}
__device__ __forceinline__ float bf2f(u16 h){
    return __uint_as_float(((u32)h) << 16);
}
__device__ __forceinline__ float fast_tanh(float x){
    float e = __builtin_amdgcn_exp2f(x * 2.8853900817779268f);  // 2*log2(e)
    return 1.0f - 2.0f * __builtin_amdgcn_rcpf(1.0f + e);
}

// split 8 fp32 -> bf16 hi + bf16 lo (error-compensated), in registers
__device__ __forceinline__ void cvt8(const float4 a, const float4 b,
                                     bf16x8& hi, bf16x8& lo){
    float xs[8] = {a.x, a.y, a.z, a.w, b.x, b.y, b.z, b.w};
    union { u16x8 u; bf16x8 b; } H, L;
    #pragma unroll
    for (int j = 0; j < 8; ++j){
        u32 u = __float_as_uint(xs[j]);
        u32 r = u + 0x7fffu + ((u >> 16) & 1u);
        H.u[j] = (u16)(r >> 16);
        float d = xs[j] - __uint_as_float(r & 0xffff0000u);
        u32 v = __float_as_uint(d);
        u32 s = v + 0x7fffu + ((v >> 16) & 1u);
        L.u[j] = (u16)(s >> 16);
    }
    hi = H.b; lo = L.b;
}

// ---------------- prep: split V into bf16 hi/lo + zero accumulators ----------------
__global__ void prep_split(const float* __restrict__ V,
                           u16* __restrict__ Vh, u16* __restrict__ Vl,
                           float* __restrict__ hsum, float* __restrict__ denom){
    int idx = blockIdx.x * 256 + threadIdx.x;   // 131072 threads
    float x = V[idx];
    u16 hi = f2bf_rne(x);
    Vh[idx] = hi;
    Vl[idx] = f2bf_rne(x - bf2f(hi));
    hsum[idx] = 0.0f;                            // hsum is exactly 131072 floats
    if (idx < NSEG * NH) denom[idx] = 0.0f;
}

// ---------------- main: persistent per-head blocks, B in registers, pipelined A ----------------
__global__ __launch_bounds__(256, 2) void medvid_main(
    const float* __restrict__ videos, const int* __restrict__ segids,
    const u16* __restrict__ Vh, const u16* __restrict__ Vl,
    const float* __restrict__ w,
    float* __restrict__ hsum, float* __restrict__ denom)
{
    __shared__ u16 sAh[BT * LDA];   // A-hi park, per-wave 16-row regions (17.4 KB)

    const int tid  = threadIdx.x;
    const int h    = blockIdx.y;
    const int c0   = blockIdx.x * CHUNK;
    const int lane = tid & 63;
    const int wv   = tid >> 6;      // wave id = 16-frame strip within tile
    const int col  = lane & 15;
    const int kb   = lane >> 4;

    // ---- B fragments: tile-invariant, fully in registers (128 VGPR) ----
    bf16x8 bh[4][4], bl[4][4];
    #pragma unroll
    for (int ks = 0; ks < 4; ++ks){
        #pragma unroll
        for (int nt = 0; nt < 4; ++nt){
            const int off = (h * LL + nt * 16 + col) * DD + kb * 8 + ks * 32;
            bh[ks][nt] = *(const bf16x8*)(Vh + off);
            bl[ks][nt] = *(const bf16x8*)(Vl + off);
        }
    }
    float wl[4];
    #pragma unroll
    for (int nt = 0; nt < 4; ++nt) wl[nt] = w[h * LL + nt * 16 + col];

    // ---- this wave's 128 segment ids (2 regs/lane): reg0 -> tiles 0..3, reg1 -> 4..7 ----
    const int segbase = c0 + kb * 64 + wv * 16 + col;
    const int mseg0 = segids[segbase];
    const int mseg1 = segids[segbase + 256];

    // ---- prologue: tile 0 A loads ----
    const float* arow = videos + (size_t)(c0 + wv * 16 + col) * 2048 + h * DD + kb * 8;
    float4 av[8];
    #pragma unroll
    for (int q = 0; q < 4; ++q){
        av[2*q]   = *(const float4*)(arow + q * 32);
        av[2*q+1] = *(const float4*)(arow + q * 32 + 4);
    }

    u16*       parkp = sAh + (wv * 16 + col) * LDA + kb * 8;
    const u16* rdp   = sAh + (wv * 16) * LDA + lane * 2;

    int   cur = -1;
    float ax = 0.f, ay = 0.f, dn = 0.f;

    for (int t = 0; t < NTILE; ++t){
        // ---- MFMA: pre-tanh alpha [16 rows x 64 L], bf16x3 compensated ----
        f32x4 acc[4] = {};
        #pragma unroll
        for (int ks = 0; ks < 4; ++ks){
            bf16x8 aH, aL;
            cvt8(av[2*ks], av[2*ks+1], aH, aL);
            *(bf16x8*)(parkp + ks * 32) = aH;        // park hi for phase-4
            #pragma unroll
            for (int nt = 0; nt < 4; ++nt){
                acc[nt] = __builtin_amdgcn_mfma_f32_16x16x32_bf16(aH, bh[ks][nt], acc[nt], 0, 0, 0);
                acc[nt] = __builtin_amdgcn_mfma_f32_16x16x32_bf16(aL, bh[ks][nt], acc[nt], 0, 0, 0);
                acc[nt] = __builtin_amdgcn_mfma_f32_16x16x32_bf16(aH, bl[ks][nt], acc[nt], 0, 0, 0);
            }
        }
        // ---- prefetch next tile's A (av regs now free) ----
        if (t + 1 < NTILE){
            const float* nrow = arow + (size_t)(t + 1) * BT * 2048;
            #pragma unroll
            for (int q = 0; q < 4; ++q){
                av[2*q]   = *(const float4*)(nrow + q * 32);
                av[2*q+1] = *(const float4*)(nrow + q * 32 + 4);
            }
        }
        // ---- tanh -> *w -> 16-lane-group reduce over L -> e ----
        float srow[4] = {0.f, 0.f, 0.f, 0.f};
        #pragma unroll
        for (int nt = 0; nt < 4; ++nt){
            #pragma unroll
            for (int r = 0; r < 4; ++r)
                srow[r] += fast_tanh(acc[nt][r]) * wl[nt];
        }
        #pragma unroll
        for (int r = 0; r < 4; ++r){
            #pragma unroll
            for (int m = 1; m < 16; m <<= 1)
                srow[r] += __shfl_xor(srow[r], m, 64);
        }
        float e4[4];
        #pragma unroll
        for (int r = 0; r < 4; ++r)
            e4[r] = __builtin_amdgcn_exp2f(srow[r] * 1.4426950408889634f);

        // ---- per-wave segment accumulation over this tile's 16 rows ----
        const int msel = (t < 4) ? mseg0 : mseg1;
        #pragma unroll
        for (int j = 0; j < 16; ++j){
            float ej = __shfl(e4[j & 3], (j >> 2) * 16);
            int   s  = __shfl(msel, (t & 3) * 16 + j);
            if (s != cur){                          // wave-uniform branch
                if (cur >= 0){
                    float* dst = hsum + ((size_t)cur * NH + h) * DD + lane * 2;
                    atomicAdd(dst, ax); atomicAdd(dst + 1, ay);
                    if (lane == 0) atomicAdd(&denom[cur * NH + h], dn);
                }
                ax = 0.f; ay = 0.f; dn = 0.f; cur = s;
            }
            u32 uh = *(const u32*)(rdp + j * LDA);
            ax += ej * __uint_as_float(uh << 16);
            ay += ej * __uint_as_float(uh & 0xffff0000u);
            dn += ej;
        }
    }
    // ---- final flush ----
    if (cur >= 0){
        float* dst = hsum + ((size_t)cur * NH + h) * DD + lane * 2;
        atomicAdd(dst, ax); atomicAdd(dst + 1, ay);
        if (lane == 0) atomicAdd(&denom[cur * NH + h], dn);
    }
}

// ---------------- finalize ----------------
__global__ void finalize(const float* __restrict__ hsum, const float* __restrict__ denom,
                         const float* __restrict__ W_out, const float* __restrict__ b_out,
                         float* __restrict__ out)
{
    const int s = blockIdx.x;
    const int tid = threadIdx.x;
    float part = 0.f;
    for (int f = tid; f < 2048; f += 256){
        int hh = f >> 7, d = f & 127;
        float den = denom[s * NH + hh];
        if (den > 0.f)
            part += hsum[((size_t)s * NH + hh) * DD + d] / (den * SCALE) * W_out[f];
    }
    #pragma unroll
    for (int m = 1; m < 64; m <<= 1) part += __shfl_xor(part, m, 64);
    __shared__ float red[4];
    if ((tid & 63) == 0) red[tid >> 6] = part;
    __syncthreads();
    if (tid == 0) out[s] = red[0] + red[1] + red[2] + red[3] + b_out[0];
}

extern "C" void kernel_launch(void* const* d_in, const int* in_sizes, int n_in,
                              void* d_out, int out_size, void* d_ws, size_t ws_size,
                              hipStream_t stream)
{
    const float* videos = (const float*)d_in[0];
    const int*   segids = (const int*)  d_in[1];
    const float* V      = (const float*)d_in[2];
    const float* w      = (const float*)d_in[3];
    const float* W_out  = (const float*)d_in[4];
    const float* b_out  = (const float*)d_in[5];
    float* out = (float*)d_out;

    // ws layout: hsum[S*H*D] f32 | denom[S*H] f32 | Vh[H*L*D] u16 | Vl[H*L*D] u16
    float* hsum  = (float*)d_ws;
    float* denom = hsum + (NSEG * NH * DD);
    u16*   Vh    = (u16*)(denom + NSEG * NH);
    u16*   Vl    = Vh + (NH * LL * DD);

    prep_split<<<dim3((NH * LL * DD) / 256), dim3(256), 0, stream>>>(V, Vh, Vl, hsum, denom);
    medvid_main<<<dim3(NCHUNK, NH), dim3(256), 0, stream>>>(videos, segids, Vh, Vl, w, hsum, denom);
    finalize<<<dim3(NSEG), dim3(256), 0, stream>>>(hsum, denom, W_out, b_out, out);
}